// Round 10
// baseline (682.173 us; speedup 1.0000x reference)
//
#include <hip/hip_runtime.h>
#include <hip/hip_fp16.h>
#include <cstdint>

#define DEV static __device__ __forceinline__

typedef _Float16 h2v __attribute__((ext_vector_type(2)));
typedef _Float16 half8 __attribute__((ext_vector_type(8)));
typedef float float4v __attribute__((ext_vector_type(4)));

union U32H2 { uint32_t u; _Float16 f[2]; };

DEV uint32_t pack_f2(float a, float b) {
    auto p = __builtin_amdgcn_cvt_pkrtz(a, b);
    return __builtin_bit_cast(uint32_t, p);
}

DEV half8 bc8(uint4 v) { return __builtin_bit_cast(half8, v); }

DEV void gl_lds16(const void* gsrc, void* ldst) {
    __builtin_amdgcn_global_load_lds(
        (const __attribute__((address_space(1))) uint32_t*)gsrc,
        (__attribute__((address_space(3))) uint32_t*)ldst, 16, 0, 0);
}

DEV float pick4(float4v lo, float4v hi, int bsel, int r) {
    float v0 = bsel ? hi[0] : lo[0];
    float v1 = bsel ? hi[1] : lo[1];
    float v2 = bsel ? hi[2] : lo[2];
    float v3 = bsel ? hi[3] : lo[3];
    float x01 = (r & 1) ? v1 : v0;
    float x23 = (r & 1) ? v3 : v2;
    return (r & 2) ? x23 : x01;
}

// ---------------- workspace layout (uint32 units) ----------------
static const size_t OFF_W16T  = 0;          // WL: 98304
static const size_t OFF_GI    = 98304;      // gs: 768 floats
static const size_t OFF_CC    = 99072;
static const size_t OFF_BF    = 99200;
static const size_t OFF_NODES = 164736;
static const size_t OFF_PF    = 263040;
static const size_t OFF_QF    = 459648;
static const size_t OFF_R0    = 656256;
static const size_t OFF_R1    = 680832;
static const size_t OFF_TT    = 705408;     // compact: [s][d][32 u32] (att1 half only)
static const size_t OFF_ATT0  = 10142592;
static const size_t OFF_DONE  = 10290048;   // completion counter for att+vout fusion
static const size_t OFF_X0    = 10535808;
static const size_t OFF_CS    = 10634112;
static const size_t WS_TOTAL  = 10634816;

// ---------------- prep: WL (Whh -> A-frags) + gs ----------------
// Kept a SEPARATE kernel: inlining into the GRU (R7) spilled the
// AGPR-resident weight array -> 2.6x loop slowdown.
__global__ void k_prep_wl(const float* __restrict__ Whh, uint32_t* __restrict__ WL,
                          const float* __restrict__ z, const float* __restrict__ Wih,
                          const float* __restrict__ bih, const float* __restrict__ bhh,
                          float* __restrict__ gs) {
    int bb = blockIdx.x, tid = threadIdx.x;
    if (bb < 48) {
        int c = bb;
        int rt = c >> 3, kt = c & 7;
        int lane = tid & 63, wv = tid >> 6;
        int row = (rt >> 1) * 256 + wv * 32 + ((rt & 1) << 4) + (lane & 15);
        int k0 = kt*32 + (lane >> 4)*8;
        const float* src = Whh + row*256 + k0;
        uint4 o;
        o.x = pack_f2(src[0], src[1]);
        o.y = pack_f2(src[2], src[3]);
        o.z = pack_f2(src[4], src[5]);
        o.w = pack_f2(src[6], src[7]);
        ((uint4*)WL)[c*512 + tid] = o;
    } else {
        int o = (bb - 48) * 512 + tid;
        if (o < 768) {
            float acc = bih[o];
            if (o < 512) acc += bhh[o];
            for (int i = 0; i < 128; ++i) acc += Wih[o*128 + i] * z[i];
            gs[o] = acc;
        }
    }
}

// ---------------- GRU segment runner (block 0 of its launch) ----------------
// h(t) == nodes[t]; a segment [t0,t1) resumes from nodes[t0-1].
DEV void gru_run(const float* __restrict__ gs, const float* __restrict__ bhh,
                 const uint32_t* __restrict__ WL, float* __restrict__ nodes,
                 _Float16* hh16, int tid, int t0, int t1) {
    int lane = tid & 63, wv = tid >> 6;
    int kq = lane >> 4, c = lane & 15;
    const float L2E = 1.44269504088896f;
    int r = c & 3, bsel = (c >> 2) & 1;
    int gidx = wv*32 + kq*4 + r + bsel*16;
    bool active = (c < 8);

    uint4 w[48];
    const uint4* wl4 = (const uint4*)WL;
    #pragma unroll
    for (int q = 0; q < 48; ++q) w[q] = wl4[q*512 + tid];
    #pragma unroll
    for (int q = 0; q < 48; ++q)
        asm volatile("" : "+a"(w[q].x), "+a"(w[q].y), "+a"(w[q].z), "+a"(w[q].w));

    float pr = -L2E * gs[gidx];
    float pz = -L2E * gs[256 + gidx];
    float pn = -2.f * L2E * gs[512 + gidx];
    float bn_l = bhh[512 + gidx];

    float h;
    if (t0 == 0) {
        h = 0.f;
        if (tid < 256) ((uint32_t*)hh16)[tid] = 0u;    // zero both buffers
    } else {
        h = nodes[(size_t)(t0-1)*256 + gidx];
        if (tid < 256) hh16[tid] = (_Float16)nodes[(size_t)(t0-1)*256 + tid];
    }
    __syncthreads();

    const float4v z4 = {0.f, 0.f, 0.f, 0.f};
    int par = 0;
    for (int t = t0; t < t1; ++t) {
        const _Float16* hb = hh16 + par*256 + kq*8;
        uint4 b[8];
        #pragma unroll
        for (int kt = 0; kt < 8; ++kt) b[kt] = *(const uint4*)(hb + kt*32);

        float4v d0, d1, d2, d3, d4, d5;
        d0 = __builtin_amdgcn_mfma_f32_16x16x32_f16(bc8(w[0]),  bc8(b[0]), z4, 0, 0, 0);
        d1 = __builtin_amdgcn_mfma_f32_16x16x32_f16(bc8(w[8]),  bc8(b[0]), z4, 0, 0, 0);
        #pragma unroll
        for (int kt = 1; kt < 8; ++kt) {
            d0 = __builtin_amdgcn_mfma_f32_16x16x32_f16(bc8(w[kt]),   bc8(b[kt]), d0, 0, 0, 0);
            d1 = __builtin_amdgcn_mfma_f32_16x16x32_f16(bc8(w[8+kt]), bc8(b[kt]), d1, 0, 0, 0);
        }
        float ghr = pick4(d0, d1, bsel, r);
        float er = __builtin_amdgcn_exp2f(__builtin_fmaf(ghr, -L2E, pr));
        float rg = __builtin_amdgcn_rcpf(1.f + er);

        d2 = __builtin_amdgcn_mfma_f32_16x16x32_f16(bc8(w[16]), bc8(b[0]), z4, 0, 0, 0);
        d3 = __builtin_amdgcn_mfma_f32_16x16x32_f16(bc8(w[24]), bc8(b[0]), z4, 0, 0, 0);
        d4 = __builtin_amdgcn_mfma_f32_16x16x32_f16(bc8(w[32]), bc8(b[0]), z4, 0, 0, 0);
        d5 = __builtin_amdgcn_mfma_f32_16x16x32_f16(bc8(w[40]), bc8(b[0]), z4, 0, 0, 0);
        #pragma unroll
        for (int kt = 1; kt < 8; ++kt) {
            d2 = __builtin_amdgcn_mfma_f32_16x16x32_f16(bc8(w[16+kt]), bc8(b[kt]), d2, 0, 0, 0);
            d3 = __builtin_amdgcn_mfma_f32_16x16x32_f16(bc8(w[24+kt]), bc8(b[kt]), d3, 0, 0, 0);
            d4 = __builtin_amdgcn_mfma_f32_16x16x32_f16(bc8(w[32+kt]), bc8(b[kt]), d4, 0, 0, 0);
            d5 = __builtin_amdgcn_mfma_f32_16x16x32_f16(bc8(w[40+kt]), bc8(b[kt]), d5, 0, 0, 0);
        }

        float ghz = pick4(d2, d3, bsel, r);
        float ghn = pick4(d4, d5, bsel, r);
        float eu = __builtin_amdgcn_exp2f(__builtin_fmaf(ghz, -L2E, pz));
        float u  = __builtin_amdgcn_rcpf(1.f + eu);
        float tm = ghn + bn_l;
        float q  = __builtin_fmaf(rg * tm, -2.f * L2E, pn);
        float e2 = __builtin_amdgcn_exp2f(q);
        float nn = __builtin_fmaf(2.f, __builtin_amdgcn_rcpf(1.f + e2), -1.f);
        h = nn + u * (h - nn);

        if (active) {
            hh16[(par ^ 1)*256 + gidx] = (_Float16)h;
            nodes[(size_t)t*256 + gidx] = h;           // HBM store: not drained at barrier
        }
        asm volatile("s_waitcnt lgkmcnt(0)" ::: "memory");
        __builtin_amdgcn_sched_barrier(0);
        __builtin_amdgcn_s_barrier();
        __builtin_amdgcn_sched_barrier(0);
        par ^= 1;
    }
}

// ---------------- pq body: 8 rows, 512 threads (tid<256: P; >=256: Q; all: R0) ----------------
DEV void pq8_body(const float* __restrict__ nodes, const float* __restrict__ egW1,
                  const float* __restrict__ egb1, const float* __restrict__ a0W1,
                  const float* __restrict__ a0b1, const float* __restrict__ cc,
                  uint32_t* __restrict__ PF, uint32_t* __restrict__ QF,
                  float* __restrict__ R0, int s0, int tid, float* ns) {
    for (int i = tid; i < 2048; i += 512)
        ns[i] = nodes[(size_t)s0*256 + i];
    __syncthreads();

    int tp = tid & 255;
    int k0 = tp * 4;
    bool isQ = tid >= 256;
    float acc[8][4];
    #pragma unroll
    for (int q = 0; q < 8; ++q) { acc[q][0]=0;acc[q][1]=0;acc[q][2]=0;acc[q][3]=0; }
    const float* Wbase = egW1 + (isQ ? (size_t)256*1024 : 0) + k0;
    for (int i = 0; i < 256; ++i) {
        float4 wv = *(const float4*)&Wbase[(size_t)i*1024];
        #pragma unroll
        for (int q = 0; q < 8; ++q) {
            float nv = ns[q*256 + i];
            acc[q][0] += nv*wv.x; acc[q][1] += nv*wv.y;
            acc[q][2] += nv*wv.z; acc[q][3] += nv*wv.w;
        }
    }
    if (!isQ) {
        float4 bv = *(const float4*)&egb1[k0];
        int kk = k0 >> 5;
        int lgrp = ((k0 >> 3) & 3) * 16;
        int sub = (k0 & 7) >> 1;
        #pragma unroll
        for (int q = 0; q < 8; ++q) {
            int s = s0 + q, g = s >> 4, srow = s & 15;
            uint2 pw;
            pw.x = pack_f2(acc[q][0] + bv.x, acc[q][1] + bv.y);
            pw.y = pack_f2(acc[q][2] + bv.z, acc[q][3] + bv.w);
            *(uint2*)(PF + (((g*32 + kk)*64 + lgrp + srow) << 2) + sub) = pw;
        }
    } else {
        #pragma unroll
        for (int q = 0; q < 8; ++q) {
            uint2 pw;
            pw.x = pack_f2(acc[q][0], acc[q][1]);
            pw.y = pack_f2(acc[q][2], acc[q][3]);
            ((uint2*)QF)[(size_t)(s0+q)*256 + tp] = pw;
        }
    }
    {
        int srow = tid >> 6, j = tid & 63;
        float racc = a0b1[j] + cc[j];
        for (int i = 0; i < 256; ++i) racc += ns[srow*256 + i] * a0W1[(128+i)*64 + j];
        R0[(size_t)(s0+srow)*64 + j] = racc;
    }
}

// ---------------- launch A: GRU steps 0..287 + BF prep (1..128) + cc (129) ----------------
__global__ void __launch_bounds__(512, 2)
k_gruA_bf(const float* __restrict__ gs, const float* __restrict__ bhh,
          const uint32_t* __restrict__ WL, float* __restrict__ nodes,
          const float* __restrict__ egW2, const float* __restrict__ egb2,
          const float* __restrict__ a0W1, const float* __restrict__ a1W1,
          uint32_t* __restrict__ BF, float* __restrict__ cc) {
    int bb = blockIdx.x, tid = threadIdx.x;
    if (bb == 0) {
        __shared__ __align__(16) _Float16 hh16[512];
        gru_run(gs, bhh, WL, nodes, hh16, tid, 0, 288);
    } else if (bb < 129) {
        int idx = (bb - 1) * 512 + tid;                // < 65536
        int k2 = idx >> 7, n = idx & 127;
        const float* A = (n < 64) ? (a0W1 + n) : (a1W1 + (n - 64));
        const float* w0 = egW2 + (2*k2) * 128;
        float a = 0.f, b = 0.f;
        for (int i = 0; i < 128; ++i) {
            float av = A[i*64];
            a += w0[i] * av;
            b += w0[128 + i] * av;
        }
        int kk = k2 >> 4, jgrp = (k2 >> 2) & 3, sub = k2 & 3;
        int lane = jgrp*16 + (n & 15), t = n >> 4;
        BF[((kk*8 + t)*64 + lane)*4 + sub] = pack_f2(a, b);
    } else {
        if (tid < 128) {
            const float* A = (tid < 64) ? a0W1 : a1W1;
            int j = tid & 63;
            float acc = 0.f;
            for (int i = 0; i < 128; ++i) acc += egb2[i] * A[i*64 + j];
            cc[tid] = acc;
        }
    }
}

// ---------------- launch B: GRU steps 288..383 + pq rows 0..287 (blocks 1..36) ----------------
__global__ void __launch_bounds__(512, 2)
k_gruB_pq(const float* __restrict__ gs, const float* __restrict__ bhh,
          const uint32_t* __restrict__ WL, float* __restrict__ nodes,
          const float* __restrict__ egW1, const float* __restrict__ egb1,
          const float* __restrict__ a0W1, const float* __restrict__ a0b1,
          const float* __restrict__ cc,
          uint32_t* __restrict__ PF, uint32_t* __restrict__ QF,
          float* __restrict__ R0) {
    __shared__ __align__(16) float smem_f[2048];       // 8 KB (pq); GRU uses first 1 KB
    int bb = blockIdx.x, tid = threadIdx.x;
    if (bb == 0) {
        gru_run(gs, bhh, WL, nodes, (_Float16*)smem_f, tid, 288, 384);
    } else {
        pq8_body(nodes, egW1, egb1, a0W1, a0b1, cc, PF, QF, R0, (bb - 1) * 8, tid, smem_f);
    }
}

// ---------------- phase A (MFMA) + fused att0; TT stores att1-half only ----------------
// variant 1: blocks 0..323 = tiles (g,dt) with g,dt<18 (need only pq rows <288);
//            blocks 324..335 = pq rows 288..383 (written here, read only by variant 2).
// variant 2: the remaining 252 tiles (g>=18 or dt>=18).
__global__ void __launch_bounds__(512, 2)
k_phaseA(const uint32_t* __restrict__ PF, const uint32_t* __restrict__ QF,
         const uint32_t* __restrict__ BF, const float* __restrict__ R0,
         const float* __restrict__ a0W2, const float* __restrict__ a0b2,
         uint32_t* __restrict__ TT, float* __restrict__ ATT0,
         const float* __restrict__ nodes, const float* __restrict__ egW1,
         const float* __restrict__ egb1, const float* __restrict__ a0W1,
         const float* __restrict__ a0b1, const float* __restrict__ cc,
         uint32_t* __restrict__ PFw, uint32_t* __restrict__ QFw,
         float* __restrict__ R0w, int variant) {
    __shared__ __align__(16) char smem[69632];
    int tid = threadIdx.x;
    int g, dt;
    if (variant == 1) {
        if (blockIdx.x >= 324) {                       // pq tail rows 288..383
            pq8_body(nodes, egW1, egb1, a0W1, a0b1, cc, PFw, QFw, R0w,
                     288 + (blockIdx.x - 324) * 8, tid, (float*)smem);
            return;
        }
        g = blockIdx.x / 18; dt = blockIdx.x % 18;
    } else {
        int id = blockIdx.x;
        if (id < 144) { dt = 18 + id / 24; g = id % 24; }
        else { int id2 = id - 144; g = 18 + id2 / 18; dt = id2 % 18; }
    }
    int d0 = dt * 16;

    uint4* Qs4 = (uint4*)smem;                         // 32 KB
    char* bufbase = smem + 32768;                      // 2 x (2KB P + 16KB B)
    int lane = tid & 63, wv = tid >> 6;

    {
        const char* src = (const char*)(QF + (size_t)d0 * 512);
        for (int off = tid*16; off < 32768; off += 8192)
            gl_lds16(src + off, (char*)Qs4 + off);
    }
    {
        const char* psrc = (const char*)(PF + (size_t)g * 8192);
        if (tid < 128) gl_lds16(psrc + tid*16, bufbase + tid*16);
        const char* bsrc = (const char*)BF;
        #pragma unroll
        for (int i = 0; i < 2; ++i)
            gl_lds16(bsrc + tid*16 + i*8192, bufbase + 2048 + tid*16 + i*8192);
    }
    asm volatile("s_waitcnt vmcnt(0)" ::: "memory");
    __builtin_amdgcn_sched_barrier(0);
    __builtin_amdgcn_s_barrier();
    __builtin_amdgcn_sched_barrier(0);

    float4v acc[2][8];
    #pragma unroll
    for (int t = 0; t < 2; ++t)
        #pragma unroll
        for (int n = 0; n < 8; ++n) acc[t][n] = 0.f;

    for (int hc = 0; hc < 16; ++hc) {
        char* cur = bufbase + (hc & 1) * 18432;
        char* nxt = bufbase + ((hc + 1) & 1) * 18432;
        if (hc < 15) {
            const char* psrc = (const char*)(PF + ((size_t)g*32 + (size_t)(hc+1)*2) * 256);
            if (tid < 128) gl_lds16(psrc + tid*16, nxt + tid*16);
            const char* bsrc = (const char*)(BF + (size_t)(hc+1) * 4096);
            #pragma unroll
            for (int i = 0; i < 2; ++i)
                gl_lds16(bsrc + tid*16 + i*8192, nxt + 2048 + tid*16 + i*8192);
        }
        uint4* Ph = (uint4*)cur;
        uint4* Bh = (uint4*)(cur + 2048);
        #pragma unroll
        for (int kkl = 0; kkl < 2; ++kkl) {
            int kkg = hc*2 + kkl;
            half8 b[8];
            #pragma unroll
            for (int n = 0; n < 8; ++n) b[n] = bc8(Bh[(kkl*8 + n)*64 + lane]);
            half8 p8 = bc8(Ph[kkl*64 + lane]);
            #pragma unroll
            for (int t = 0; t < 2; ++t) {
                half8 q8 = bc8(Qs4[(wv*2 + t)*128 + kkg*4 + (lane >> 4)]);
                half8 x = p8 + q8;
                half8 zz = 0;
                x = __builtin_elementwise_max(x, zz);
                #pragma unroll
                for (int n = 0; n < 8; ++n)
                    acc[t][n] = __builtin_amdgcn_mfma_f32_16x16x32_f16(x, b[n], acc[t][n], 0, 0, 0);
            }
        }
        asm volatile("s_waitcnt vmcnt(0)" ::: "memory");
        __builtin_amdgcn_sched_barrier(0);
        __builtin_amdgcn_s_barrier();
        __builtin_amdgcn_sched_barrier(0);
    }

    __syncthreads();
    float* R0s = (float*)smem;                         // reuse Q region
    float* w2s = (float*)(smem + 4096);
    for (int i = tid; i < 1024; i += 512)
        R0s[i] = R0[(size_t)(g*16 + (i >> 6))*64 + (i & 63)];
    if (tid < 64) w2s[tid] = a0W2[tid];
    float b2v = a0b2[0];

    _Float16* epi = (_Float16*)(smem + 32768);
    int cn = lane & 15, rhi = (lane >> 4) * 4;
    for (int half = 0; half < 2; ++half) {
        __syncthreads();
        #pragma unroll
        for (int t = 0; t < 2; ++t) {
            int dl = wv*2 + t;
            #pragma unroll
            for (int n = 0; n < 4; ++n) {
                int j = n*16 + cn;
                float4v v = acc[t][half*4 + n];
                #pragma unroll
                for (int r = 0; r < 4; ++r)
                    epi[((rhi + r)*16 + dl)*64 + j] = (_Float16)v[r];
            }
        }
        __syncthreads();
        if (half == 1) {                               // att1 features 64..127 only
            int p = tid >> 1, sub = tid & 1;
            int srow = p >> 4, dl = p & 15;
            const uint4* src = (const uint4*)(epi + (size_t)p*64);
            uint4* dst = (uint4*)(TT + ((size_t)((g*16 + srow)*384 + d0 + dl))*32);
            #pragma unroll
            for (int q = 0; q < 4; ++q) dst[sub*4 + q] = src[sub*4 + q];
        }
        if (half == 0 && tid < 256) {
            int sl = tid >> 4, dl = tid & 15;
            const _Float16* tp = epi + (size_t)(sl*16 + dl)*64;
            const float* rp = R0s + sl*64;
            float logit = b2v;
            #pragma unroll
            for (int j = 0; j < 64; ++j)
                logit += fmaxf((float)tp[j] + rp[j], 0.f) * w2s[j];
            float a = 1.f / (1.f + __expf(-logit));
            int s = g*16 + sl, d = d0 + dl;
            ATT0[(size_t)s*384 + d] = (s == d) ? 0.f : a;
        }
    }
}

// ---------------- attention att1 (compact TT) -> column sums; last block does vout ----------------
__global__ void k_att(const uint32_t* __restrict__ TT, const float* __restrict__ R,
                      const float* __restrict__ w2, const float* __restrict__ b2,
                      float* __restrict__ CS, uint32_t* __restrict__ done,
                      const float* __restrict__ X0, const float* __restrict__ c1W,
                      const float* __restrict__ c1b, float* __restrict__ out) {
    int tid = threadIdx.x;
    int p = blockIdx.x * 256 + tid;
    int s = p / 384, d = p - s * 384;
    int sa = (blockIdx.x * 256) / 384;
    __shared__ float w2s[64];
    __shared__ float rs[2][64];
    if (tid < 64) w2s[tid] = w2[tid];
    else if (tid < 128) rs[0][tid - 64] = R[sa*64 + (tid - 64)];
    else if (tid < 192) {
        int sb = sa + 1;
        rs[1][tid - 128] = (sb < 384) ? R[sb*64 + (tid - 128)] : 0.f;
    }
    __syncthreads();
    const uint4* tp = (const uint4*)(TT + (size_t)p*32);
    const float* rp = (s == sa) ? rs[0] : rs[1];
    float logit = b2[0];
    #pragma unroll
    for (int m = 0; m < 8; ++m) {
        uint4 tv = tp[m];
        uint32_t us[4] = {tv.x, tv.y, tv.z, tv.w};
        #pragma unroll
        for (int q = 0; q < 4; ++q) {
            U32H2 c; c.u = us[q];
            int j = m*8 + q*2;
            float h0 = fmaxf((float)c.f[0] + rp[j],   0.f);
            float h1 = fmaxf((float)c.f[1] + rp[j+1], 0.f);
            logit += h0*w2s[j] + h1*w2s[j+1];
        }
    }
    float a = 1.f / (1.f + __expf(-logit));
    float a_eff = (s == d) ? 0.f : a;

    float va = (s == sa) ? a_eff : 0.f;
    float vb = (s != sa) ? a_eff : 0.f;
    #pragma unroll
    for (int o = 32; o > 0; o >>= 1) {
        va += __shfl_down(va, o, 64);
        vb += __shfl_down(vb, o, 64);
    }
    if ((tid & 63) == 0) {
        atomicAdd(&CS[sa], va);
        int sb = sa + 1;
        if (sb < 384) atomicAdd(&CS[sb], vb);
    }

    // ---- completion: last block computes vout (single check, no spinning) ----
    __threadfence();
    __syncthreads();
    __shared__ int last_s;
    if (tid == 0) {
        uint32_t v = __hip_atomic_fetch_add(done, 1u, __ATOMIC_ACQ_REL, __HIP_MEMORY_SCOPE_AGENT);
        last_s = (v == 575);
    }
    __syncthreads();
    if (!last_s) return;

    __shared__ float cs[384];
    __shared__ float vs[256];
    for (int q = tid; q < 384; q += 256)
        cs[q] = __hip_atomic_load(&CS[q], __ATOMIC_ACQUIRE, __HIP_MEMORY_SCOPE_AGENT);
    __syncthreads();
    float acc = 0.f;
    for (int ss = 0; ss < 384; ss += 4) {
        acc += cs[ss]*X0[ss*256 + tid] + cs[ss+1]*X0[(ss+1)*256 + tid]
             + cs[ss+2]*X0[(ss+2)*256 + tid] + cs[ss+3]*X0[(ss+3)*256 + tid];
    }
    vs[tid] = acc;
    __syncthreads();
    float o = 384.f * c1b[tid];
    for (int i = 0; i < 256; ++i) o += vs[i] * c1W[i*256 + tid];
    out[tid] = o;
}

// ---------------- fused agg + conv0 linear + R1 (one block per d); zeros CS/done ----------------
__global__ void __launch_bounds__(256)
k_aggx0(const float* __restrict__ ATT, const float* __restrict__ X,
        const float* __restrict__ W, const float* __restrict__ b,
        const float* __restrict__ a1W1, const float* __restrict__ a1b1,
        const float* __restrict__ cc,
        float* __restrict__ X0, float* __restrict__ R1,
        float* __restrict__ CS, uint32_t* __restrict__ done) {
    int d = blockIdx.x, tid = threadIdx.x;
    if (d == 0) {                                      // CS/done zero (att runs strictly after)
        for (int s = tid; s < 384; s += 256) CS[s] = 0.f;
        if (tid == 0) *done = 0u;
    }
    __shared__ float att_col[384];
    __shared__ float ag[256];
    __shared__ float xs[256];
    __shared__ float part[4][64];
    for (int s = tid; s < 384; s += 256) att_col[s] = ATT[(size_t)s*384 + d];
    __syncthreads();
    float acc = 0.f;
    #pragma unroll 4
    for (int s = 0; s < 384; ++s)
        acc += att_col[s] * X[(size_t)s*256 + tid];
    ag[tid] = acc;
    __syncthreads();
    float x0 = b[tid];
    for (int i = 0; i < 256; ++i) x0 += ag[i] * W[i*256 + tid];
    x0 = fmaxf(x0, 0.f);
    X0[(size_t)d*256 + tid] = x0;
    xs[tid] = x0;
    __syncthreads();
    {
        int j = tid & 63, qd = tid >> 6;
        float r = 0.f;
        int i0 = qd * 64;
        for (int i = i0; i < i0 + 64; ++i) r += xs[i] * a1W1[(128+i)*64 + j];
        part[qd][j] = r;
    }
    __syncthreads();
    if (tid < 64) {
        R1[(size_t)d*64 + tid] = a1b1[tid] + cc[64 + tid]
            + part[0][tid] + part[1][tid] + part[2][tid] + part[3][tid];
    }
}

extern "C" void kernel_launch(void* const* d_in, const int* in_sizes, int n_in,
                              void* d_out, int out_size, void* d_ws, size_t ws_size,
                              hipStream_t stream) {
    if (ws_size < WS_TOTAL * sizeof(uint32_t)) return;

    const float* z    = (const float*)d_in[0];
    const float* Wih  = (const float*)d_in[1];
    const float* Whh  = (const float*)d_in[2];
    const float* bih  = (const float*)d_in[3];
    const float* bhh  = (const float*)d_in[4];
    const float* egW1 = (const float*)d_in[5];
    const float* egb1 = (const float*)d_in[6];
    const float* egW2 = (const float*)d_in[7];
    const float* egb2 = (const float*)d_in[8];
    const float* a0W1 = (const float*)d_in[9];
    const float* a0b1 = (const float*)d_in[10];
    const float* a0W2 = (const float*)d_in[11];
    const float* a0b2 = (const float*)d_in[12];
    const float* a1W1 = (const float*)d_in[13];
    const float* a1b1 = (const float*)d_in[14];
    const float* a1W2 = (const float*)d_in[15];
    const float* a1b2 = (const float*)d_in[16];
    const float* c0W  = (const float*)d_in[17];
    const float* c0b  = (const float*)d_in[18];
    const float* c1W  = (const float*)d_in[19];
    const float* c1b  = (const float*)d_in[20];

    uint32_t* ws   = (uint32_t*)d_ws;
    uint32_t* WL   = ws + OFF_W16T;
    float*    gs   = (float*)(ws + OFF_GI);
    float*    cc   = (float*)(ws + OFF_CC);
    uint32_t* BF   = ws + OFF_BF;
    float*    nodes= (float*)(ws + OFF_NODES);
    uint32_t* PF   = ws + OFF_PF;
    uint32_t* QF   = ws + OFF_QF;
    float*    R0   = (float*)(ws + OFF_R0);
    float*    R1   = (float*)(ws + OFF_R1);
    uint32_t* TT   = ws + OFF_TT;
    float*    ATT0 = (float*)(ws + OFF_ATT0);
    uint32_t* done = ws + OFF_DONE;
    float*    X0   = (float*)(ws + OFF_X0);
    float*    CS   = (float*)(ws + OFF_CS);
    float*    out  = (float*)d_out;

    hipLaunchKernelGGL(k_prep_wl, dim3(50),  dim3(512), 0, stream, Whh, WL, z, Wih, bih, bhh, gs);
    hipLaunchKernelGGL(k_gruA_bf, dim3(130), dim3(512), 0, stream, gs, bhh, WL, nodes,
                       egW2, egb2, a0W1, a1W1, BF, cc);
    hipLaunchKernelGGL(k_gruB_pq, dim3(37),  dim3(512), 0, stream, gs, bhh, WL, nodes,
                       egW1, egb1, a0W1, a0b1, cc, PF, QF, R0);
    hipLaunchKernelGGL(k_phaseA,  dim3(336), dim3(512), 0, stream, PF, QF, BF, R0, a0W2, a0b2,
                       TT, ATT0, nodes, egW1, egb1, a0W1, a0b1, cc, PF, QF, R0, 1);
    hipLaunchKernelGGL(k_phaseA,  dim3(252), dim3(512), 0, stream, PF, QF, BF, R0, a0W2, a0b2,
                       TT, ATT0, nodes, egW1, egb1, a0W1, a0b1, cc, PF, QF, R0, 2);
    hipLaunchKernelGGL(k_aggx0,   dim3(384), dim3(256), 0, stream, ATT0, nodes, c0W, c0b,
                       a1W1, a1b1, cc, X0, R1, CS, done);
    hipLaunchKernelGGL(k_att,     dim3(576), dim3(256), 0, stream, TT, R1, a1W2, a1b2,
                       CS, done, X0, c1W, c1b, out);
}

// Round 11
// 649.496 us; speedup vs baseline: 1.0503x; 1.0503x over previous
//
#include <hip/hip_runtime.h>
#include <hip/hip_fp16.h>
#include <cstdint>

#define DEV static __device__ __forceinline__

typedef _Float16 h2v __attribute__((ext_vector_type(2)));
typedef _Float16 half8 __attribute__((ext_vector_type(8)));
typedef float float4v __attribute__((ext_vector_type(4)));

union U32H2 { uint32_t u; _Float16 f[2]; };

DEV uint32_t pack_f2(float a, float b) {
    auto p = __builtin_amdgcn_cvt_pkrtz(a, b);
    return __builtin_bit_cast(uint32_t, p);
}

DEV half8 bc8(uint4 v) { return __builtin_bit_cast(half8, v); }

DEV void gl_lds16(const void* gsrc, void* ldst) {
    __builtin_amdgcn_global_load_lds(
        (const __attribute__((address_space(1))) uint32_t*)gsrc,
        (__attribute__((address_space(3))) uint32_t*)ldst, 16, 0, 0);
}

DEV float pick4(float4v lo, float4v hi, int bsel, int r) {
    float v0 = bsel ? hi[0] : lo[0];
    float v1 = bsel ? hi[1] : lo[1];
    float v2 = bsel ? hi[2] : lo[2];
    float v3 = bsel ? hi[3] : lo[3];
    float x01 = (r & 1) ? v1 : v0;
    float x23 = (r & 1) ? v3 : v2;
    return (r & 2) ? x23 : x01;
}

// ---------------- workspace layout (uint32 units) ----------------
static const size_t OFF_W16T  = 0;          // WL: 98304
static const size_t OFF_GI    = 98304;      // gs: 768 floats
static const size_t OFF_CC    = 99072;
static const size_t OFF_BF    = 99200;
static const size_t OFF_NODES = 164736;
static const size_t OFF_PF    = 263040;
static const size_t OFF_QF    = 459648;
static const size_t OFF_R0    = 656256;
static const size_t OFF_R1    = 680832;
static const size_t OFF_TT    = 705408;     // compact: [s][d][32 u32] (att1 half only)
static const size_t OFF_ATT0  = 10142592;
static const size_t OFF_ATT1  = 10290048;   // unused (dead store removed)
static const size_t OFF_X0    = 10535808;
static const size_t OFF_CS    = 10634112;
static const size_t WS_TOTAL  = 10634816;

// ---------------- prep: WL (Whh -> A-frags) + gs ----------------
// Kept a SEPARATE kernel: inlining into the GRU (R7) spilled the
// AGPR-resident weight array -> 2.6x loop slowdown.
__global__ void k_prep_wl(const float* __restrict__ Whh, uint32_t* __restrict__ WL,
                          const float* __restrict__ z, const float* __restrict__ Wih,
                          const float* __restrict__ bih, const float* __restrict__ bhh,
                          float* __restrict__ gs) {
    int bb = blockIdx.x, tid = threadIdx.x;
    if (bb < 48) {
        int c = bb;
        int rt = c >> 3, kt = c & 7;
        int lane = tid & 63, wv = tid >> 6;
        int row = (rt >> 1) * 256 + wv * 32 + ((rt & 1) << 4) + (lane & 15);
        int k0 = kt*32 + (lane >> 4)*8;
        const float* src = Whh + row*256 + k0;
        uint4 o;
        o.x = pack_f2(src[0], src[1]);
        o.y = pack_f2(src[2], src[3]);
        o.z = pack_f2(src[4], src[5]);
        o.w = pack_f2(src[6], src[7]);
        ((uint4*)WL)[c*512 + tid] = o;
    } else {
        int o = (bb - 48) * 512 + tid;
        if (o < 768) {
            float acc = bih[o];
            if (o < 512) acc += bhh[o];
            for (int i = 0; i < 128; ++i) acc += Wih[o*128 + i] * z[i];
            gs[o] = acc;
        }
    }
}

// ---------------- GRU segment runner (block 0 of its launch) ----------------
// h(t) == nodes[t]; a segment [t0,t1) resumes from nodes[t0-1].
DEV void gru_run(const float* __restrict__ gs, const float* __restrict__ bhh,
                 const uint32_t* __restrict__ WL, float* __restrict__ nodes,
                 _Float16* hh16, int tid, int t0, int t1) {
    int lane = tid & 63, wv = tid >> 6;
    int kq = lane >> 4, c = lane & 15;
    const float L2E = 1.44269504088896f;
    int r = c & 3, bsel = (c >> 2) & 1;
    int gidx = wv*32 + kq*4 + r + bsel*16;
    bool active = (c < 8);

    uint4 w[48];
    const uint4* wl4 = (const uint4*)WL;
    #pragma unroll
    for (int q = 0; q < 48; ++q) w[q] = wl4[q*512 + tid];
    #pragma unroll
    for (int q = 0; q < 48; ++q)
        asm volatile("" : "+a"(w[q].x), "+a"(w[q].y), "+a"(w[q].z), "+a"(w[q].w));

    float pr = -L2E * gs[gidx];
    float pz = -L2E * gs[256 + gidx];
    float pn = -2.f * L2E * gs[512 + gidx];
    float bn_l = bhh[512 + gidx];

    float h;
    if (t0 == 0) {
        h = 0.f;
        if (tid < 256) ((uint32_t*)hh16)[tid] = 0u;    // zero both buffers
    } else {
        h = nodes[(size_t)(t0-1)*256 + gidx];
        if (tid < 256) hh16[tid] = (_Float16)nodes[(size_t)(t0-1)*256 + tid];
    }
    __syncthreads();

    const float4v z4 = {0.f, 0.f, 0.f, 0.f};
    int par = 0;
    for (int t = t0; t < t1; ++t) {
        const _Float16* hb = hh16 + par*256 + kq*8;
        uint4 b[8];
        #pragma unroll
        for (int kt = 0; kt < 8; ++kt) b[kt] = *(const uint4*)(hb + kt*32);

        float4v d0, d1, d2, d3, d4, d5;
        d0 = __builtin_amdgcn_mfma_f32_16x16x32_f16(bc8(w[0]),  bc8(b[0]), z4, 0, 0, 0);
        d1 = __builtin_amdgcn_mfma_f32_16x16x32_f16(bc8(w[8]),  bc8(b[0]), z4, 0, 0, 0);
        #pragma unroll
        for (int kt = 1; kt < 8; ++kt) {
            d0 = __builtin_amdgcn_mfma_f32_16x16x32_f16(bc8(w[kt]),   bc8(b[kt]), d0, 0, 0, 0);
            d1 = __builtin_amdgcn_mfma_f32_16x16x32_f16(bc8(w[8+kt]), bc8(b[kt]), d1, 0, 0, 0);
        }
        float ghr = pick4(d0, d1, bsel, r);
        float er = __builtin_amdgcn_exp2f(__builtin_fmaf(ghr, -L2E, pr));
        float rg = __builtin_amdgcn_rcpf(1.f + er);

        d2 = __builtin_amdgcn_mfma_f32_16x16x32_f16(bc8(w[16]), bc8(b[0]), z4, 0, 0, 0);
        d3 = __builtin_amdgcn_mfma_f32_16x16x32_f16(bc8(w[24]), bc8(b[0]), z4, 0, 0, 0);
        d4 = __builtin_amdgcn_mfma_f32_16x16x32_f16(bc8(w[32]), bc8(b[0]), z4, 0, 0, 0);
        d5 = __builtin_amdgcn_mfma_f32_16x16x32_f16(bc8(w[40]), bc8(b[0]), z4, 0, 0, 0);
        #pragma unroll
        for (int kt = 1; kt < 8; ++kt) {
            d2 = __builtin_amdgcn_mfma_f32_16x16x32_f16(bc8(w[16+kt]), bc8(b[kt]), d2, 0, 0, 0);
            d3 = __builtin_amdgcn_mfma_f32_16x16x32_f16(bc8(w[24+kt]), bc8(b[kt]), d3, 0, 0, 0);
            d4 = __builtin_amdgcn_mfma_f32_16x16x32_f16(bc8(w[32+kt]), bc8(b[kt]), d4, 0, 0, 0);
            d5 = __builtin_amdgcn_mfma_f32_16x16x32_f16(bc8(w[40+kt]), bc8(b[kt]), d5, 0, 0, 0);
        }

        float ghz = pick4(d2, d3, bsel, r);
        float ghn = pick4(d4, d5, bsel, r);
        float eu = __builtin_amdgcn_exp2f(__builtin_fmaf(ghz, -L2E, pz));
        float u  = __builtin_amdgcn_rcpf(1.f + eu);
        float tm = ghn + bn_l;
        float q  = __builtin_fmaf(rg * tm, -2.f * L2E, pn);
        float e2 = __builtin_amdgcn_exp2f(q);
        float nn = __builtin_fmaf(2.f, __builtin_amdgcn_rcpf(1.f + e2), -1.f);
        h = nn + u * (h - nn);

        if (active) {
            hh16[(par ^ 1)*256 + gidx] = (_Float16)h;
            nodes[(size_t)t*256 + gidx] = h;           // HBM store: not drained at barrier
        }
        asm volatile("s_waitcnt lgkmcnt(0)" ::: "memory");
        __builtin_amdgcn_sched_barrier(0);
        __builtin_amdgcn_s_barrier();
        __builtin_amdgcn_sched_barrier(0);
        par ^= 1;
    }
}

// ---------------- pq body: 8 rows, 512 threads (tid<256: P; >=256: Q; all: R0) ----------------
DEV void pq8_body(const float* __restrict__ nodes, const float* __restrict__ egW1,
                  const float* __restrict__ egb1, const float* __restrict__ a0W1,
                  const float* __restrict__ a0b1, const float* __restrict__ cc,
                  uint32_t* __restrict__ PF, uint32_t* __restrict__ QF,
                  float* __restrict__ R0, int s0, int tid, float* ns) {
    for (int i = tid; i < 2048; i += 512)
        ns[i] = nodes[(size_t)s0*256 + i];
    __syncthreads();

    int tp = tid & 255;
    int k0 = tp * 4;
    bool isQ = tid >= 256;
    float acc[8][4];
    #pragma unroll
    for (int q = 0; q < 8; ++q) { acc[q][0]=0;acc[q][1]=0;acc[q][2]=0;acc[q][3]=0; }
    const float* Wbase = egW1 + (isQ ? (size_t)256*1024 : 0) + k0;
    for (int i = 0; i < 256; ++i) {
        float4 wv = *(const float4*)&Wbase[(size_t)i*1024];
        #pragma unroll
        for (int q = 0; q < 8; ++q) {
            float nv = ns[q*256 + i];
            acc[q][0] += nv*wv.x; acc[q][1] += nv*wv.y;
            acc[q][2] += nv*wv.z; acc[q][3] += nv*wv.w;
        }
    }
    if (!isQ) {
        float4 bv = *(const float4*)&egb1[k0];
        int kk = k0 >> 5;
        int lgrp = ((k0 >> 3) & 3) * 16;
        int sub = (k0 & 7) >> 1;
        #pragma unroll
        for (int q = 0; q < 8; ++q) {
            int s = s0 + q, g = s >> 4, srow = s & 15;
            uint2 pw;
            pw.x = pack_f2(acc[q][0] + bv.x, acc[q][1] + bv.y);
            pw.y = pack_f2(acc[q][2] + bv.z, acc[q][3] + bv.w);
            *(uint2*)(PF + (((g*32 + kk)*64 + lgrp + srow) << 2) + sub) = pw;
        }
    } else {
        #pragma unroll
        for (int q = 0; q < 8; ++q) {
            uint2 pw;
            pw.x = pack_f2(acc[q][0], acc[q][1]);
            pw.y = pack_f2(acc[q][2], acc[q][3]);
            ((uint2*)QF)[(size_t)(s0+q)*256 + tp] = pw;
        }
    }
    {
        int srow = tid >> 6, j = tid & 63;
        float racc = a0b1[j] + cc[j];
        for (int i = 0; i < 256; ++i) racc += ns[srow*256 + i] * a0W1[(128+i)*64 + j];
        R0[(size_t)(s0+srow)*64 + j] = racc;
    }
}

// ---------------- launch A: GRU steps 0..287 + BF prep (1..128) + cc (129) ----------------
__global__ void __launch_bounds__(512, 2)
k_gruA_bf(const float* __restrict__ gs, const float* __restrict__ bhh,
          const uint32_t* __restrict__ WL, float* __restrict__ nodes,
          const float* __restrict__ egW2, const float* __restrict__ egb2,
          const float* __restrict__ a0W1, const float* __restrict__ a1W1,
          uint32_t* __restrict__ BF, float* __restrict__ cc) {
    int bb = blockIdx.x, tid = threadIdx.x;
    if (bb == 0) {
        __shared__ __align__(16) _Float16 hh16[512];
        gru_run(gs, bhh, WL, nodes, hh16, tid, 0, 288);
    } else if (bb < 129) {
        int idx = (bb - 1) * 512 + tid;                // < 65536
        int k2 = idx >> 7, n = idx & 127;
        const float* A = (n < 64) ? (a0W1 + n) : (a1W1 + (n - 64));
        const float* w0 = egW2 + (2*k2) * 128;
        float a = 0.f, b = 0.f;
        for (int i = 0; i < 128; ++i) {
            float av = A[i*64];
            a += w0[i] * av;
            b += w0[128 + i] * av;
        }
        int kk = k2 >> 4, jgrp = (k2 >> 2) & 3, sub = k2 & 3;
        int lane = jgrp*16 + (n & 15), t = n >> 4;
        BF[((kk*8 + t)*64 + lane)*4 + sub] = pack_f2(a, b);
    } else {
        if (tid < 128) {
            const float* A = (tid < 64) ? a0W1 : a1W1;
            int j = tid & 63;
            float acc = 0.f;
            for (int i = 0; i < 128; ++i) acc += egb2[i] * A[i*64 + j];
            cc[tid] = acc;
        }
    }
}

// ---------------- launch B: GRU steps 288..383 + pq rows 0..287 (blocks 1..36) ----------------
__global__ void __launch_bounds__(512, 2)
k_gruB_pq(const float* __restrict__ gs, const float* __restrict__ bhh,
          const uint32_t* __restrict__ WL, float* __restrict__ nodes,
          const float* __restrict__ egW1, const float* __restrict__ egb1,
          const float* __restrict__ a0W1, const float* __restrict__ a0b1,
          const float* __restrict__ cc,
          uint32_t* __restrict__ PF, uint32_t* __restrict__ QF,
          float* __restrict__ R0) {
    __shared__ __align__(16) float smem_f[2048];       // 8 KB (pq); GRU uses first 1 KB
    int bb = blockIdx.x, tid = threadIdx.x;
    if (bb == 0) {
        gru_run(gs, bhh, WL, nodes, (_Float16*)smem_f, tid, 288, 384);
    } else {
        pq8_body(nodes, egW1, egb1, a0W1, a0b1, cc, PF, QF, R0, (bb - 1) * 8, tid, smem_f);
    }
}

// ---------------- pq tail: rows 288..383 ----------------
__global__ void __launch_bounds__(512)
k_pq_tail(const float* __restrict__ nodes, const float* __restrict__ egW1,
          const float* __restrict__ egb1, const float* __restrict__ a0W1,
          const float* __restrict__ a0b1, const float* __restrict__ cc,
          uint32_t* __restrict__ PF, uint32_t* __restrict__ QF,
          float* __restrict__ R0) {
    __shared__ __align__(16) float smem_f[2048];
    pq8_body(nodes, egW1, egb1, a0W1, a0b1, cc, PF, QF, R0, 288 + blockIdx.x * 8,
             threadIdx.x, smem_f);
}

// ---------------- phase A (MFMA) + fused att0; TT stores att1-half only ----------------
__global__ void __launch_bounds__(512, 4)
k_phaseA(const uint32_t* __restrict__ PF, const uint32_t* __restrict__ QF,
         const uint32_t* __restrict__ BF, const float* __restrict__ R0,
         const float* __restrict__ a0W2, const float* __restrict__ a0b2,
         uint32_t* __restrict__ TT, float* __restrict__ ATT0) {
    __shared__ __align__(16) char smem[69632];
    uint4* Qs4 = (uint4*)smem;                         // 32 KB
    char* bufbase = smem + 32768;                      // 2 x (2KB P + 16KB B)
    int tid = threadIdx.x;
    int lane = tid & 63, wv = tid >> 6;
    int g = blockIdx.x, dt = blockIdx.y, d0 = dt * 16;

    {
        const char* src = (const char*)(QF + (size_t)d0 * 512);
        for (int off = tid*16; off < 32768; off += 8192)
            gl_lds16(src + off, (char*)Qs4 + off);
    }
    {
        const char* psrc = (const char*)(PF + (size_t)g * 8192);
        if (tid < 128) gl_lds16(psrc + tid*16, bufbase + tid*16);
        const char* bsrc = (const char*)BF;
        #pragma unroll
        for (int i = 0; i < 2; ++i)
            gl_lds16(bsrc + tid*16 + i*8192, bufbase + 2048 + tid*16 + i*8192);
    }
    asm volatile("s_waitcnt vmcnt(0)" ::: "memory");
    __builtin_amdgcn_sched_barrier(0);
    __builtin_amdgcn_s_barrier();
    __builtin_amdgcn_sched_barrier(0);

    float4v acc[2][8];
    #pragma unroll
    for (int t = 0; t < 2; ++t)
        #pragma unroll
        for (int n = 0; n < 8; ++n) acc[t][n] = 0.f;

    for (int hc = 0; hc < 16; ++hc) {
        char* cur = bufbase + (hc & 1) * 18432;
        char* nxt = bufbase + ((hc + 1) & 1) * 18432;
        if (hc < 15) {
            const char* psrc = (const char*)(PF + ((size_t)g*32 + (size_t)(hc+1)*2) * 256);
            if (tid < 128) gl_lds16(psrc + tid*16, nxt + tid*16);
            const char* bsrc = (const char*)(BF + (size_t)(hc+1) * 4096);
            #pragma unroll
            for (int i = 0; i < 2; ++i)
                gl_lds16(bsrc + tid*16 + i*8192, nxt + 2048 + tid*16 + i*8192);
        }
        uint4* Ph = (uint4*)cur;
        uint4* Bh = (uint4*)(cur + 2048);
        #pragma unroll
        for (int kkl = 0; kkl < 2; ++kkl) {
            int kkg = hc*2 + kkl;
            half8 b[8];
            #pragma unroll
            for (int n = 0; n < 8; ++n) b[n] = bc8(Bh[(kkl*8 + n)*64 + lane]);
            half8 p8 = bc8(Ph[kkl*64 + lane]);
            #pragma unroll
            for (int t = 0; t < 2; ++t) {
                half8 q8 = bc8(Qs4[(wv*2 + t)*128 + kkg*4 + (lane >> 4)]);
                half8 x = p8 + q8;
                half8 zz = 0;
                x = __builtin_elementwise_max(x, zz);
                #pragma unroll
                for (int n = 0; n < 8; ++n)
                    acc[t][n] = __builtin_amdgcn_mfma_f32_16x16x32_f16(x, b[n], acc[t][n], 0, 0, 0);
            }
        }
        asm volatile("s_waitcnt vmcnt(0)" ::: "memory");
        __builtin_amdgcn_sched_barrier(0);
        __builtin_amdgcn_s_barrier();
        __builtin_amdgcn_sched_barrier(0);
    }

    __syncthreads();
    float* R0s = (float*)smem;                         // reuse Q region
    float* w2s = (float*)(smem + 4096);
    for (int i = tid; i < 1024; i += 512)
        R0s[i] = R0[(size_t)(g*16 + (i >> 6))*64 + (i & 63)];
    if (tid < 64) w2s[tid] = a0W2[tid];
    float b2v = a0b2[0];

    _Float16* epi = (_Float16*)(smem + 32768);
    int cn = lane & 15, rhi = (lane >> 4) * 4;
    for (int half = 0; half < 2; ++half) {
        __syncthreads();
        #pragma unroll
        for (int t = 0; t < 2; ++t) {
            int dl = wv*2 + t;
            #pragma unroll
            for (int n = 0; n < 4; ++n) {
                int j = n*16 + cn;
                float4v v = acc[t][half*4 + n];
                #pragma unroll
                for (int r = 0; r < 4; ++r)
                    epi[((rhi + r)*16 + dl)*64 + j] = (_Float16)v[r];
            }
        }
        __syncthreads();
        if (half == 1) {                               // att1 features 64..127 only
            int p = tid >> 1, sub = tid & 1;
            int srow = p >> 4, dl = p & 15;
            const uint4* src = (const uint4*)(epi + (size_t)p*64);
            uint4* dst = (uint4*)(TT + ((size_t)((g*16 + srow)*384 + d0 + dl))*32);
            #pragma unroll
            for (int q = 0; q < 4; ++q) dst[sub*4 + q] = src[sub*4 + q];
        }
        if (half == 0 && tid < 256) {
            int sl = tid >> 4, dl = tid & 15;
            const _Float16* tp = epi + (size_t)(sl*16 + dl)*64;
            const float* rp = R0s + sl*64;
            float logit = b2v;
            #pragma unroll
            for (int j = 0; j < 64; ++j)
                logit += fmaxf((float)tp[j] + rp[j], 0.f) * w2s[j];
            float a = 1.f / (1.f + __expf(-logit));
            int s = g*16 + sl, d = d0 + dl;
            ATT0[(size_t)s*384 + d] = (s == d) ? 0.f : a;
        }
    }
}

// ---------------- attention att1 (compact TT) -> column sums only ----------------
__global__ void k_att(const uint32_t* __restrict__ TT, const float* __restrict__ R,
                      const float* __restrict__ w2, const float* __restrict__ b2,
                      float* __restrict__ CS) {
    int tid = threadIdx.x;
    int p = blockIdx.x * 256 + tid;
    int s = p / 384, d = p - s * 384;
    int sa = (blockIdx.x * 256) / 384;
    __shared__ float w2s[64];
    __shared__ float rs[2][64];
    if (tid < 64) w2s[tid] = w2[tid];
    else if (tid < 128) rs[0][tid - 64] = R[sa*64 + (tid - 64)];
    else if (tid < 192) {
        int sb = sa + 1;
        rs[1][tid - 128] = (sb < 384) ? R[sb*64 + (tid - 128)] : 0.f;
    }
    __syncthreads();
    const uint4* tp = (const uint4*)(TT + (size_t)p*32);
    const float* rp = (s == sa) ? rs[0] : rs[1];
    float logit = b2[0];
    #pragma unroll
    for (int m = 0; m < 8; ++m) {
        uint4 tv = tp[m];
        uint32_t us[4] = {tv.x, tv.y, tv.z, tv.w};
        #pragma unroll
        for (int q = 0; q < 4; ++q) {
            U32H2 c; c.u = us[q];
            int j = m*8 + q*2;
            float h0 = fmaxf((float)c.f[0] + rp[j],   0.f);
            float h1 = fmaxf((float)c.f[1] + rp[j+1], 0.f);
            logit += h0*w2s[j] + h1*w2s[j+1];
        }
    }
    float a = 1.f / (1.f + __expf(-logit));
    float a_eff = (s == d) ? 0.f : a;

    float va = (s == sa) ? a_eff : 0.f;
    float vb = (s != sa) ? a_eff : 0.f;
    #pragma unroll
    for (int o = 32; o > 0; o >>= 1) {
        va += __shfl_down(va, o, 64);
        vb += __shfl_down(vb, o, 64);
    }
    if ((tid & 63) == 0) {
        atomicAdd(&CS[sa], va);
        int sb = sa + 1;
        if (sb < 384) atomicAdd(&CS[sb], vb);
    }
}

// ---------------- fused agg + conv0 linear + R1 (one block per d); zeros CS ----------------
__global__ void __launch_bounds__(256)
k_aggx0(const float* __restrict__ ATT, const float* __restrict__ X,
        const float* __restrict__ W, const float* __restrict__ b,
        const float* __restrict__ a1W1, const float* __restrict__ a1b1,
        const float* __restrict__ cc,
        float* __restrict__ X0, float* __restrict__ R1, float* __restrict__ CS) {
    int d = blockIdx.x, tid = threadIdx.x;
    if (d == 0) {                                      // CS zero (att1 runs strictly after)
        for (int s = tid; s < 384; s += 256) CS[s] = 0.f;
    }
    __shared__ float att_col[384];
    __shared__ float ag[256];
    __shared__ float xs[256];
    for (int s = tid; s < 384; s += 256) att_col[s] = ATT[(size_t)s*384 + d];
    __syncthreads();
    float acc = 0.f;
    #pragma unroll 4
    for (int s = 0; s < 384; ++s)
        acc += att_col[s] * X[(size_t)s*256 + tid];
    ag[tid] = acc;
    __syncthreads();
    float x0 = b[tid];
    for (int i = 0; i < 256; ++i) x0 += ag[i] * W[i*256 + tid];
    x0 = fmaxf(x0, 0.f);
    X0[(size_t)d*256 + tid] = x0;
    xs[tid] = x0;
    __syncthreads();
    if (tid < 64) {
        float r = a1b1[tid] + cc[64 + tid];
        for (int i = 0; i < 256; ++i) r += xs[i] * a1W1[(128+i)*64 + tid];
        R1[(size_t)d*64 + tid] = r;
    }
}

// ---------------- fused V + out (single block) ----------------
__global__ void k_vout(const float* __restrict__ CS, const float* __restrict__ X0,
                       const float* __restrict__ W, const float* __restrict__ b,
                       float* __restrict__ out) {
    int tid = threadIdx.x;
    __shared__ float cs[384];
    __shared__ float vs[256];
    for (int q = tid; q < 384; q += 256) cs[q] = CS[q];
    __syncthreads();
    float acc = 0.f;
    for (int s = 0; s < 384; s += 4) {
        acc += cs[s]*X0[s*256 + tid] + cs[s+1]*X0[(s+1)*256 + tid]
             + cs[s+2]*X0[(s+2)*256 + tid] + cs[s+3]*X0[(s+3)*256 + tid];
    }
    vs[tid] = acc;
    __syncthreads();
    float o = 384.f * b[tid];
    for (int i = 0; i < 256; ++i) o += vs[i] * W[i*256 + tid];
    out[tid] = o;
}

extern "C" void kernel_launch(void* const* d_in, const int* in_sizes, int n_in,
                              void* d_out, int out_size, void* d_ws, size_t ws_size,
                              hipStream_t stream) {
    if (ws_size < WS_TOTAL * sizeof(uint32_t)) return;

    const float* z    = (const float*)d_in[0];
    const float* Wih  = (const float*)d_in[1];
    const float* Whh  = (const float*)d_in[2];
    const float* bih  = (const float*)d_in[3];
    const float* bhh  = (const float*)d_in[4];
    const float* egW1 = (const float*)d_in[5];
    const float* egb1 = (const float*)d_in[6];
    const float* egW2 = (const float*)d_in[7];
    const float* egb2 = (const float*)d_in[8];
    const float* a0W1 = (const float*)d_in[9];
    const float* a0b1 = (const float*)d_in[10];
    const float* a0W2 = (const float*)d_in[11];
    const float* a0b2 = (const float*)d_in[12];
    const float* a1W1 = (const float*)d_in[13];
    const float* a1b1 = (const float*)d_in[14];
    const float* a1W2 = (const float*)d_in[15];
    const float* a1b2 = (const float*)d_in[16];
    const float* c0W  = (const float*)d_in[17];
    const float* c0b  = (const float*)d_in[18];
    const float* c1W  = (const float*)d_in[19];
    const float* c1b  = (const float*)d_in[20];

    uint32_t* ws   = (uint32_t*)d_ws;
    uint32_t* WL   = ws + OFF_W16T;
    float*    gs   = (float*)(ws + OFF_GI);
    float*    cc   = (float*)(ws + OFF_CC);
    uint32_t* BF   = ws + OFF_BF;
    float*    nodes= (float*)(ws + OFF_NODES);
    uint32_t* PF   = ws + OFF_PF;
    uint32_t* QF   = ws + OFF_QF;
    float*    R0   = (float*)(ws + OFF_R0);
    float*    R1   = (float*)(ws + OFF_R1);
    uint32_t* TT   = ws + OFF_TT;
    float*    ATT0 = (float*)(ws + OFF_ATT0);
    float*    X0   = (float*)(ws + OFF_X0);
    float*    CS   = (float*)(ws + OFF_CS);
    float*    out  = (float*)d_out;

    hipLaunchKernelGGL(k_prep_wl, dim3(50),     dim3(512), 0, stream, Whh, WL, z, Wih, bih, bhh, gs);
    hipLaunchKernelGGL(k_gruA_bf, dim3(130),    dim3(512), 0, stream, gs, bhh, WL, nodes,
                       egW2, egb2, a0W1, a1W1, BF, cc);
    hipLaunchKernelGGL(k_gruB_pq, dim3(37),     dim3(512), 0, stream, gs, bhh, WL, nodes,
                       egW1, egb1, a0W1, a0b1, cc, PF, QF, R0);
    hipLaunchKernelGGL(k_pq_tail, dim3(12),     dim3(512), 0, stream, nodes, egW1, egb1,
                       a0W1, a0b1, cc, PF, QF, R0);
    hipLaunchKernelGGL(k_phaseA,  dim3(24, 24), dim3(512), 0, stream, PF, QF, BF, R0, a0W2, a0b2, TT, ATT0);
    hipLaunchKernelGGL(k_aggx0,   dim3(384),    dim3(256), 0, stream, ATT0, nodes, c0W, c0b, a1W1, a1b1, cc, X0, R1, CS);
    hipLaunchKernelGGL(k_att,     dim3(576),    dim3(256), 0, stream, TT, R1, a1W2, a1b2, CS);
    hipLaunchKernelGGL(k_vout,    dim3(1),      dim3(256), 0, stream, CS, X0, c1W, c1b, out);
}